// Round 2
// baseline (89.158 us; speedup 1.0000x reference)
//
#include <hip/hip_runtime.h>

// CausalGraphLayer: out[b,n,t,c] = tanh( sum_k z[b, idx[n,k], t, c] * w[n,k,c] )
//   w[n,k,c] = adj[n,k] * sum_bb cc[c,bb] * bw[bb,n,k]
// B=2, N=2048, T=32, C=32, NBASE=4, MAXK=32, KC=16.
//
// R8: R7 retry — NON-TEMPORAL OUT STORES via native clang vector type
//  (__builtin_nontemporal_store rejects HIP_vector_type<float,4>; it accepts
//   a clang ext_vector_type. Same dwordx4 store, nt bit set.)
//  Theory: timed graph = 43 µs harness poison-fill (HBM-roofline, fixed) +
//  ~30 small reset dispatches + this kernel (<42 µs, modeled 8-20 µs).
//  If out-store traffic (2 MB/XCD/pass) evicts the 2 MB/XCD z gather
//  line-set from the 4 MB L2, nt stores recover L2 gather hits.
//  Predict: thrash-case dur 87->78-82 µs; else unchanged (harness floor).
//
//  Carried from R6:
//  - R2 XCD-pinned (b,tq) t-quarter slices -> per-XCD gather set 2 MB (L2-resident)
//  - fp32 gather (no bf16 prepass: R5 showed prepass cost == gather saving)
//  - R4 scalar (SGPR) neighbor indices + all 16 gathers issued before the
//    w-compute barrier (loads in flight across __syncthreads)
//  - lean preamble: tables staged by disjoint thread ranges, no idx LDS trip

constexpr int BB_    = 2;
constexpr int NN_    = 2048;
constexpr int TT_    = 32;
constexpr int CC_    = 32;
constexpr int NBASE_ = 4;
constexpr int MAXK_  = 32;
constexpr int KC_    = 16;

constexpr int TQ_      = 4;                  // t-quarters
constexpr int NODES_PB = 4;                  // nodes per block (1 per wave)
constexpr int PLANE4_  = TT_ * CC_ / 4;      // 256 float4 per (b,n)
constexpr int SLICE4_  = (TT_ / TQ_) * CC_ / 4;  // 64 float4 per (n,tq)

typedef float f32x4 __attribute__((ext_vector_type(4)));

__device__ __forceinline__ float fast_tanh(float x) {
    float e = __expf(2.0f * x);
    float r = __builtin_amdgcn_rcpf(e + 1.0f);
    return fmaf(-2.0f, r, 1.0f);
}

__global__ __launch_bounds__(256, 4) void cgl_kernel(
    const float* __restrict__ z,     // [B,N,T,C]
    const int*   __restrict__ nbr,   // [N,KC]
    const float* __restrict__ adj,   // [N,MAXK]
    const float* __restrict__ bw,    // [NBASE,N,MAXK]
    const float* __restrict__ cc,    // [C,NBASE]
    float*       __restrict__ out)   // [B,N,T,C]
{
    __shared__ __align__(16) float w_s[NODES_PB][KC_][CC_];  // 8 KB
    __shared__ float bw_s[NODES_PB][NBASE_][KC_];            // 1 KB
    __shared__ float cc_s[NBASE_][CC_];                      // 512 B (transposed)
    __shared__ float adj_s[NODES_PB][KC_];

    const int tid = threadIdx.x;
    const int blk = blockIdx.x;

    // XCD-pinned (b, tq): blk % 8 -> XCD round-robin.
    const int xcd   = blk & 7;
    const int b     = xcd >> 2;
    const int tq    = xcd & 3;
    const int group = blk >> 3;          // 0..511
    const int node0 = group * NODES_PB;

    const int wave = tid >> 6;
    const int lane = tid & 63;
    const int n    = node0 + wave;

    // ---- per-wave SGPR neighbor indices (block-uniform within wave) ----
    const int* __restrict__ ip = nbr + n * KC_;
    int nks[KC_];
    #pragma unroll
    for (int k = 0; k < KC_; ++k)
        nks[k] = __builtin_amdgcn_readfirstlane(ip[k]);

    // ---- issue ALL 16 fp32 gathers (1 KB / wave-instr, contiguous) ----
    float4 zv[KC_];
    {
        const float4* __restrict__ z4 =
            (const float4*)z + (size_t)b * NN_ * PLANE4_ + (size_t)tq * SLICE4_ + lane;
        #pragma unroll
        for (int k = 0; k < KC_; ++k)
            zv[k] = z4[(size_t)nks[k] * PLANE4_];
    }

    // ---- stage per-node tables into LDS (disjoint thread ranges) ----
    {   // bw: 256 values, one per thread
        int nd = tid >> 6, bb = (tid >> 4) & 3, k = tid & 15;
        bw_s[nd][bb][k] = bw[((size_t)bb * NN_ + (node0 + nd)) * MAXK_ + k];

        if (tid < 64) {                          // adj: node|k
            int nd2 = tid >> 4, k2 = tid & 15;
            adj_s[nd2][k2] = adj[(size_t)(node0 + nd2) * MAXK_ + k2];
        } else if (tid < 192) {                  // cc transposed [bb][c]
            int i = tid - 64, bb2 = i >> 5, c2 = i & 31;
            cc_s[bb2][c2] = cc[c2 * NBASE_ + bb2];
        }
    }
    __syncthreads();

    // ---- compute w[nd][k][c]: 2048 cells, 8 per thread ----
    {
        int i = tid;
        #pragma unroll
        for (int r = 0; r < 8; ++r, i += 256) {
            int nd = i >> 9, k = (i >> 5) & 15, c = i & 31;
            float s = cc_s[0][c] * bw_s[nd][0][k]
                    + cc_s[1][c] * bw_s[nd][1][k]
                    + cc_s[2][c] * bw_s[nd][2][k]
                    + cc_s[3][c] * bw_s[nd][3][k];
            w_s[nd][k][c] = s * adj_s[nd][k];
        }
    }
    __syncthreads();

    // ---- FMA reduction (zv loads drained by compiler waitcnt here) ----
    const int c0 = (lane << 2) & 31;
    float4 acc = make_float4(0.f, 0.f, 0.f, 0.f);
    #pragma unroll
    for (int k = 0; k < KC_; ++k) {
        float4 wv = *(const float4*)&w_s[wave][k][c0];   // 8-way broadcast, no conflict
        acc.x = fmaf(zv[k].x, wv.x, acc.x);
        acc.y = fmaf(zv[k].y, wv.y, acc.y);
        acc.z = fmaf(zv[k].z, wv.z, acc.z);
        acc.w = fmaf(zv[k].w, wv.w, acc.w);
    }

    f32x4 o;
    o.x = fast_tanh(acc.x);
    o.y = fast_tanh(acc.y);
    o.z = fast_tanh(acc.z);
    o.w = fast_tanh(acc.w);

    // contiguous 1 KB store per wave — NON-TEMPORAL: out is write-once,
    // never re-read; keep it from evicting the z gather set in L2.
    f32x4* op = (f32x4*)out + (size_t)(b * NN_ + n) * PLANE4_ + tq * SLICE4_;
    __builtin_nontemporal_store(o, op + lane);
}

extern "C" void kernel_launch(void* const* d_in, const int* in_sizes, int n_in,
                              void* d_out, int out_size, void* d_ws, size_t ws_size,
                              hipStream_t stream) {
    const float* z   = (const float*)d_in[0];
    const int*   nbr = (const int*)d_in[1];
    const float* adj = (const float*)d_in[2];
    const float* bw  = (const float*)d_in[3];
    const float* cc  = (const float*)d_in[4];
    float* out = (float*)d_out;

    cgl_kernel<<<dim3(BB_ * TQ_ * (NN_ / NODES_PB)), dim3(256), 0, stream>>>(
        z, nbr, adj, bw, cc, out);
}

// Round 3
// 88.239 us; speedup vs baseline: 1.0104x; 1.0104x over previous
//
#include <hip/hip_runtime.h>

// CausalGraphLayer: out[b,n,t,c] = tanh( sum_k z[b, idx[n,k], t, c] * w[n,k,c] )
//   w[n,k,c] = adj[n,k] * sum_bb cc[c,bb] * bw[bb,n,k]
// B=2, N=2048, T=32, C=32, NBASE=4, MAXK=32, KC=16.
//
// R9: REVERT to verified-best R6 config (plain dwordx4 store).
//  R8 A/B result: nt-stores null-to-slightly-negative (87.3->89.2, of which
//  ~+1 us was harness-fill variance). L2-write-thrash theory refuted.
//  Decomposition of the 87 us timed loop:
//    43-44 us  harness 268MB poison fill @ HBM ceiling (fixed)
//    ~30-34 us ~30 harness reset dispatches (fixed)
//    ~10 us    this kernel (modeled floor ~8 us: 32MB/XCD L2 gather @4.3TB/s)
//  Remaining in-kernel headroom <= ~2-3 us == run-to-run noise band.
//
//  Carried (verified best-of across R0-R6):
//  - R2 XCD-pinned (b,tq) t-quarter slices -> per-XCD gather set 2 MB (L2-resident)
//  - fp32 gather (no bf16 prepass: R5 showed prepass cost == gather saving)
//  - R4 scalar (SGPR) neighbor indices + all 16 gathers issued before the
//    w-compute barrier (loads in flight across __syncthreads)
//  - lean preamble: tables staged by disjoint thread ranges, no idx LDS trip

constexpr int BB_    = 2;
constexpr int NN_    = 2048;
constexpr int TT_    = 32;
constexpr int CC_    = 32;
constexpr int NBASE_ = 4;
constexpr int MAXK_  = 32;
constexpr int KC_    = 16;

constexpr int TQ_      = 4;                  // t-quarters
constexpr int NODES_PB = 4;                  // nodes per block (1 per wave)
constexpr int PLANE4_  = TT_ * CC_ / 4;      // 256 float4 per (b,n)
constexpr int SLICE4_  = (TT_ / TQ_) * CC_ / 4;  // 64 float4 per (n,tq)

__device__ __forceinline__ float fast_tanh(float x) {
    float e = __expf(2.0f * x);
    float r = __builtin_amdgcn_rcpf(e + 1.0f);
    return fmaf(-2.0f, r, 1.0f);
}

__global__ __launch_bounds__(256, 4) void cgl_kernel(
    const float* __restrict__ z,     // [B,N,T,C]
    const int*   __restrict__ nbr,   // [N,KC]
    const float* __restrict__ adj,   // [N,MAXK]
    const float* __restrict__ bw,    // [NBASE,N,MAXK]
    const float* __restrict__ cc,    // [C,NBASE]
    float*       __restrict__ out)   // [B,N,T,C]
{
    __shared__ __align__(16) float w_s[NODES_PB][KC_][CC_];  // 8 KB
    __shared__ float bw_s[NODES_PB][NBASE_][KC_];            // 1 KB
    __shared__ float cc_s[NBASE_][CC_];                      // 512 B (transposed)
    __shared__ float adj_s[NODES_PB][KC_];

    const int tid = threadIdx.x;
    const int blk = blockIdx.x;

    // XCD-pinned (b, tq): blk % 8 -> XCD round-robin.
    const int xcd   = blk & 7;
    const int b     = xcd >> 2;
    const int tq    = xcd & 3;
    const int group = blk >> 3;          // 0..511
    const int node0 = group * NODES_PB;

    const int wave = tid >> 6;
    const int lane = tid & 63;
    const int n    = node0 + wave;

    // ---- per-wave SGPR neighbor indices (block-uniform within wave) ----
    const int* __restrict__ ip = nbr + n * KC_;
    int nks[KC_];
    #pragma unroll
    for (int k = 0; k < KC_; ++k)
        nks[k] = __builtin_amdgcn_readfirstlane(ip[k]);

    // ---- issue ALL 16 fp32 gathers (1 KB / wave-instr, contiguous) ----
    float4 zv[KC_];
    {
        const float4* __restrict__ z4 =
            (const float4*)z + (size_t)b * NN_ * PLANE4_ + (size_t)tq * SLICE4_ + lane;
        #pragma unroll
        for (int k = 0; k < KC_; ++k)
            zv[k] = z4[(size_t)nks[k] * PLANE4_];
    }

    // ---- stage per-node tables into LDS (disjoint thread ranges) ----
    {   // bw: 256 values, one per thread
        int nd = tid >> 6, bb = (tid >> 4) & 3, k = tid & 15;
        bw_s[nd][bb][k] = bw[((size_t)bb * NN_ + (node0 + nd)) * MAXK_ + k];

        if (tid < 64) {                          // adj: node|k
            int nd2 = tid >> 4, k2 = tid & 15;
            adj_s[nd2][k2] = adj[(size_t)(node0 + nd2) * MAXK_ + k2];
        } else if (tid < 192) {                  // cc transposed [bb][c]
            int i = tid - 64, bb2 = i >> 5, c2 = i & 31;
            cc_s[bb2][c2] = cc[c2 * NBASE_ + bb2];
        }
    }
    __syncthreads();

    // ---- compute w[nd][k][c]: 2048 cells, 8 per thread ----
    {
        int i = tid;
        #pragma unroll
        for (int r = 0; r < 8; ++r, i += 256) {
            int nd = i >> 9, k = (i >> 5) & 15, c = i & 31;
            float s = cc_s[0][c] * bw_s[nd][0][k]
                    + cc_s[1][c] * bw_s[nd][1][k]
                    + cc_s[2][c] * bw_s[nd][2][k]
                    + cc_s[3][c] * bw_s[nd][3][k];
            w_s[nd][k][c] = s * adj_s[nd][k];
        }
    }
    __syncthreads();

    // ---- FMA reduction (zv loads drained by compiler waitcnt here) ----
    const int c0 = (lane << 2) & 31;
    float4 acc = make_float4(0.f, 0.f, 0.f, 0.f);
    #pragma unroll
    for (int k = 0; k < KC_; ++k) {
        float4 wv = *(const float4*)&w_s[wave][k][c0];   // 8-way broadcast, no conflict
        acc.x = fmaf(zv[k].x, wv.x, acc.x);
        acc.y = fmaf(zv[k].y, wv.y, acc.y);
        acc.z = fmaf(zv[k].z, wv.z, acc.z);
        acc.w = fmaf(zv[k].w, wv.w, acc.w);
    }

    float4 o;
    o.x = fast_tanh(acc.x);
    o.y = fast_tanh(acc.y);
    o.z = fast_tanh(acc.z);
    o.w = fast_tanh(acc.w);

    // contiguous 1 KB store per wave
    float4* op = (float4*)out + (size_t)(b * NN_ + n) * PLANE4_ + tq * SLICE4_;
    op[lane] = o;
}

extern "C" void kernel_launch(void* const* d_in, const int* in_sizes, int n_in,
                              void* d_out, int out_size, void* d_ws, size_t ws_size,
                              hipStream_t stream) {
    const float* z   = (const float*)d_in[0];
    const int*   nbr = (const int*)d_in[1];
    const float* adj = (const float*)d_in[2];
    const float* bw  = (const float*)d_in[3];
    const float* cc  = (const float*)d_in[4];
    float* out = (float*)d_out;

    cgl_kernel<<<dim3(BB_ * TQ_ * (NN_ / NODES_PB)), dim3(256), 0, stream>>>(
        z, nbr, adj, bw, cc, out);
}